// Round 2
// baseline (331.905 us; speedup 1.0000x reference)
//
#include <hip/hip_runtime.h>
#include <math.h>

// Dims (hard-coded per reference setup_inputs)
#define NN 64
#define CIN 64
#define COUT 64
#define TT 256
#define VV 17
#define NSUB 3
#define GG 8

// ws layout (float units):
//  [0      .. 6144)  Mb   u16[3][8][32w][16k]  (bf16, M^T per (s,g): Mb[w][k]=M[v=k][w]; w>=17 -> 0)
//  [6144   .. 6912)  Mrow16 f32[3][8][32]      (M[s,g,v=16,w]; w>=17 -> 0)
//  [6912   .. 13056) Wbf  u16[192][64]         (bf16 conv weight)
//  [13056  .. 17152) psum f32[64][64]
//  [17152  .. 21248) ssq  f32[64][64]
//  after pass1, Mb/Wbf regions are dead:
//  [0      .. 4096)  acoef f32[64][64]
//  [4096   .. 8192)  bcoef f32[64][64]
#define WS_MB 0
#define WS_MR16 6144
#define WS_WBF 6912
#define WS_PSUM 13056
#define WS_SSQ 17152
#define WS_ACOEF 0
#define WS_BCOEF 4096

typedef short bh8 __attribute__((ext_vector_type(8)));
typedef short bh4 __attribute__((ext_vector_type(4)));
typedef float f32x4 __attribute__((ext_vector_type(4)));
typedef float f32x16 __attribute__((ext_vector_type(16)));

__device__ __forceinline__ unsigned bf16r(float f) {
    unsigned u = __builtin_bit_cast(unsigned, f);
    return (u + 0x7fffu + ((u >> 16) & 1u)) >> 16;  // RNE f32->bf16
}
__device__ __forceinline__ float bf2f(unsigned short us) {
    return __builtin_bit_cast(float, ((unsigned)us) << 16);
}

// ---------------- Kernel 1: prep — build bf16 M^T table, v16 row, bf16 W; zero stats ----------------
__device__ __forceinline__ float mfull(const float* Ab, const float* DA, const float* DAM,
                                       int s, int g, int v, int w) {
    const unsigned bad = (1u << 3) | (1u << 6) | (1u << 7) | (1u << 9) | (1u << 10);
    float mask = ((v >= 12 && w >= 12) || ((bad >> v) & 1) || ((bad >> w) & 1)) ? 0.f : 1.f;
    int src = ((s * GG + g) * VV + v) * VV + w;
    return Ab[(s * VV + v) * VV + w] + DA[src] + DAM[src] * mask + 0.04f;
}

__global__ void gcn_prep(const float* __restrict__ Ab, const float* __restrict__ DA,
                         const float* __restrict__ DAM, const float* __restrict__ convw,
                         float* __restrict__ ws) {
    int t0 = blockIdx.x * 256 + threadIdx.x;
    int stride = gridDim.x * 256;
    unsigned short* wbf = (unsigned short*)(ws + WS_WBF);
    for (int i = t0; i < 192 * 64; i += stride) wbf[i] = (unsigned short)bf16r(convw[i]);
    unsigned short* mb = (unsigned short*)(ws + WS_MB);
    for (int i = t0; i < NSUB * GG * 32 * 16; i += stride) {
        int k = i & 15, w = (i >> 4) & 31, g = (i >> 9) & 7, s = i >> 12;
        unsigned short val = 0;
        if (w < VV) val = (unsigned short)bf16r(mfull(Ab, DA, DAM, s, g, k, w));
        mb[i] = val;
    }
    float* mr = ws + WS_MR16;
    for (int i = t0; i < NSUB * GG * 32; i += stride) {
        int w = i & 31, g = (i >> 5) & 7, s = i >> 8;
        mr[i] = (w < VV) ? mfull(Ab, DA, DAM, s, g, 16, w) : 0.f;
    }
    for (int i = t0; i < 8192; i += stride) ws[WS_PSUM + i] = 0.f;
}

// ---------------- Kernel 2: fused conv(MFMA) + adjacency(MFMA) + m2 store + stats ----------------
// Tile = (n, 16 timesteps) -> 272 tv-columns. 1024 tiles, 256 blocks x 4 tiles.
// LDS: xsT [272 col][72 ci-pad] bf16 (transposed x tile)  = 39168 B
//      mt  [64 co][16 t][20 v-pad] bf16 (+ m16 [64][20])  = 43520 B
__global__ __launch_bounds__(512, 2) void gcn_pass1(const float* __restrict__ x,
                                                    const float* __restrict__ convb,
                                                    const float* __restrict__ ws,
                                                    float* __restrict__ out,
                                                    float* __restrict__ psum,
                                                    float* __restrict__ ssq) {
    __shared__ unsigned xsT[9792];                    // u32 view; bf16 [272][72]
    __shared__ unsigned short mt[20480 + 1280];       // [64][16][20] + m16 [64][20]

    const int tid = threadIdx.x;
    const int wave = tid >> 6;        // 0..7 == adjacency group g
    const int l = tid & 63;
    const int c16 = l & 15;
    const int q4 = (l >> 4) & 3;
    const int c32 = l & 31;
    const int hi = l >> 5;

    const unsigned short* mb16 = (const unsigned short*)(ws + WS_MB);
    const float* mrow16 = ws + WS_MR16;
    const unsigned short* wbf = (const unsigned short*)(ws + WS_WBF);
    const unsigned short* xsT16 = (const unsigned short*)xsT;

    // Adjacency B-fragments + v16 row: loaded ONCE (constant across tiles).
    // B[k=v][col=w] for mfma_32x32x16: lane(col=l&31, k=8*(l>>5)+j) -> Mb[s][g][w=c32][8*hi + j]
    bh8 Badj[3];
    float mr16v[3];
#pragma unroll
    for (int s = 0; s < 3; ++s) {
        Badj[s] = *(const bh8*)&mb16[((s * 8 + wave) * 32 + c32) * 16 + 8 * hi];
        mr16v[s] = mrow16[(s * 8 + wave) * 32 + c32];
    }
    const int cfs[3] = {wave, wave + 8, 16};  // conv col-frag set (cf=16 duplicated by all waves)

    for (int tl = blockIdx.x; tl < 1024; tl += 256) {
        const int n = tl >> 4;
        const int tt = tl & 15;

        // ---- stage x tile transposed: xsT[col][ci] bf16, ci-pairs packed in u32 ----
        const float* xb = x + (size_t)n * 64 * 4352 + tt * 272;
#pragma unroll
        for (int k = 0; k < 4; ++k) {
            int cp = wave + 8 * k;  // ci pair index
            const float* r0 = xb + (2 * cp) * 4352;
            const float* r1 = r0 + 4352;
#pragma unroll
            for (int cc = 0; cc < 5; ++cc) {
                int col = cc * 64 + l;
                if (col < 272) {
                    unsigned p = bf16r(r0[col]) | (bf16r(r1[col]) << 16);
                    xsT[col * 36 + cp] = p;
                }
            }
        }
        __syncthreads();

        // ---- conv B-fragments from xsT (s-invariant; b128, conflict-free) ----
        // B[k=ci][col=tv]: lane(col=l&15, k=32ks+8*(l>>4)+j)
        bh8 Bc[3][2];
#pragma unroll
        for (int cfi = 0; cfi < 3; ++cfi)
#pragma unroll
            for (int ks = 0; ks < 2; ++ks)
                Bc[cfi][ks] = *(const bh8*)&xsT16[(16 * cfs[cfi] + c16) * 72 + 32 * ks + 8 * q4];

        f32x16 D2[4];
#pragma unroll
        for (int p = 0; p < 4; ++p) D2[p] = 0;

#pragma unroll
        for (int s = 0; s < 3; ++s) {
            // ---- conv MFMA: rows = 64 co of subset s ----
            f32x4 Dc[4][3];
#pragma unroll
            for (int rf = 0; rf < 4; ++rf) {
                f32x4 bias = *(const f32x4*)(convb + s * 64 + 16 * rf + 4 * q4);
#pragma unroll
                for (int cfi = 0; cfi < 3; ++cfi) Dc[rf][cfi] = bias;
            }
#pragma unroll
            for (int rf = 0; rf < 4; ++rf)
#pragma unroll
                for (int ks = 0; ks < 2; ++ks) {
                    // A[row=Krow][k=ci]: lane(row=l&15, k=32ks+8*(l>>4)+j)
                    bh8 A = *(const bh8*)&wbf[(s * 64 + 16 * rf + c16) * 64 + 32 * ks + 8 * q4];
#pragma unroll
                    for (int cfi = 0; cfi < 3; ++cfi)
                        Dc[rf][cfi] = __builtin_amdgcn_mfma_f32_16x16x32_bf16(A, Bc[cfi][ks],
                                                                              Dc[rf][cfi], 0, 0, 0);
                }
            // ---- store m (bf16) into mt[co][t][v] / m16[co][t] ----
#pragma unroll
            for (int rf = 0; rf < 4; ++rf)
#pragma unroll
                for (int cfi = 0; cfi < 3; ++cfi) {
                    int col = 16 * cfs[cfi] + c16;
                    int t = (col * 241) >> 12;  // col/17, exact for col<272
                    int v = col - 17 * t;
#pragma unroll
                    for (int i = 0; i < 4; ++i) {
                        int co = 16 * rf + 4 * q4 + i;
                        unsigned short us = (unsigned short)bf16r(Dc[rf][cfi][i]);
                        int idx = (v < 16) ? (co * 320 + t * 20 + v) : (20480 + co * 20 + t);
                        mt[idx] = us;
                    }
                }
            __syncthreads();

            // ---- adjacency MFMA: D2[p] += m[32 rows=(cosel,t)][v] * M[v][w] ----
#pragma unroll
            for (int p = 0; p < 4; ++p) {
                int coA = wave + 8 * (2 * p + (c32 >> 4));  // A row = c32 -> (cosel=c32>>4, t=c16)
                int addr = coA * 320 + c16 * 20 + 8 * hi;   // k = 8*(l>>5)+j
                bh4 a0 = *(const bh4*)&mt[addr];
                bh4 a1 = *(const bh4*)&mt[addr + 4];
                bh8 a = __builtin_shufflevector(a0, a1, 0, 1, 2, 3, 4, 5, 6, 7);
                D2[p] = __builtin_amdgcn_mfma_f32_32x32x16_bf16(a, Badj[s], D2[p], 0, 0, 0);
                // v=16 fixup: D[row][w] += m16[co(row)][t(row)] * M[16][w]
#pragma unroll
                for (int rq = 0; rq < 4; ++rq) {
                    int cosel = rq >> 1;
                    int t0 = 8 * (rq & 1) + 4 * hi;
                    int co16 = wave + 8 * (2 * p + cosel);
                    bh4 m4 = *(const bh4*)&mt[20480 + co16 * 20 + t0];
#pragma unroll
                    for (int j = 0; j < 4; ++j)
                        D2[p][4 * rq + j] += bf2f((unsigned short)m4[j]) * mr16v[s];
                }
            }
            __syncthreads();
        }

        // ---- epilogue: m2 stores (f32 to d_out) + stats ----
#pragma unroll
        for (int p = 0; p < 4; ++p) {
            float s1a = 0.f, s2a = 0.f, s1b = 0.f, s2b = 0.f;
#pragma unroll
            for (int reg = 0; reg < 16; ++reg) {
                int row = (reg & 3) + 8 * (reg >> 2) + 4 * hi;
                int cosel = row >> 4;
                int t = row & 15;
                int co = wave + 8 * (2 * p + cosel);
                float val = D2[p][reg];
                if (c32 < 17)
                    out[(((n * 64 + co) * 256 + tt * 16 + t)) * 17 + c32] = val;
                // pad cols w>=17 are exactly 0 (Mb/Mrow16 zeros) -> safe to include
                if (reg < 8) { s1a += val; s2a += val * val; }
                else         { s1b += val; s2b += val * val; }
            }
#pragma unroll
            for (int m = 1; m < 64; m <<= 1) {
                s1a += __shfl_xor(s1a, m);
                s2a += __shfl_xor(s2a, m);
                s1b += __shfl_xor(s1b, m);
                s2b += __shfl_xor(s2b, m);
            }
            if (l == 0) {
                atomicAdd(&psum[n * 64 + wave + 16 * p], s1a);
                atomicAdd(&ssq[n * 64 + wave + 16 * p], s2a);
                atomicAdd(&psum[n * 64 + wave + 16 * p + 8], s1b);
                atomicAdd(&ssq[n * 64 + wave + 16 * p + 8], s2b);
            }
        }
    }
}

// ---------------- Kernel 3: SE gate + BN stats -> per-(n,c) affine coefs ----------------
__global__ void gcn_stats(const float* __restrict__ se_w, const float* __restrict__ gamma,
                          const float* __restrict__ beta, float* __restrict__ ws) {
    __shared__ float ps[4096], sc[4096], q2s[4096];
    __shared__ float mu_s[64], inv_s[64];
    int tid = threadIdx.x;
    const float* psum = ws + WS_PSUM;
    const float* ssq = ws + WS_SSQ;
    float* acoef = ws + WS_ACOEF;
    float* bcoef = ws + WS_BCOEF;
    for (int i = tid; i < 4096; i += 256) ps[i] = psum[i] * (1.f / (TT * VV));
    __syncthreads();
    float w0 = se_w[0], w1 = se_w[1], w2 = se_w[2];
    for (int i = tid; i < 4096; i += 256) {
        int c = i & 63;
        float pm = (c > 0) ? ps[i - 1] : 0.f;
        float pp = (c < 63) ? ps[i + 1] : 0.f;
        float gg = w0 * pm + w1 * ps[i] + w2 * pp;
        float s = 1.f + 1.f / (1.f + expf(-gg));
        sc[i] = s;
        q2s[i] = s * s * ssq[i];
    }
    __syncthreads();
    if (tid < 64) {
        float mu = 0.f, e2 = 0.f;
        for (int nn = 0; nn < 64; ++nn) {
            mu += sc[nn * 64 + tid] * ps[nn * 64 + tid];
            e2 += q2s[nn * 64 + tid];
        }
        mu *= (1.f / 64.f);
        e2 *= (1.f / (64.f * TT * VV));
        float var = e2 - mu * mu;
        mu_s[tid] = mu;
        inv_s[tid] = rsqrtf(var + 1e-5f);
    }
    __syncthreads();
    for (int i = tid; i < 4096; i += 256) {
        int c = i & 63;
        float gin = gamma[c] * inv_s[c];
        acoef[i] = gin * sc[i];
        bcoef[i] = beta[c] - gin * mu_s[c];
    }
}

// ---------------- Kernel 4: out = relu(a*m2 + b + x), in-place on d_out ----------------
__global__ __launch_bounds__(256) void gcn_final(const float* __restrict__ x,
                                                 const float* __restrict__ ws,
                                                 float* __restrict__ out) {
    const float* acoef = ws + WS_ACOEF;
    const float* bcoef = ws + WS_BCOEF;
    int i = blockIdx.x * 256 + threadIdx.x;
    const int total4 = (NN * COUT * TT * VV) / 4;
    if (i >= total4) return;
    int nc = i / ((TT * VV) / 4);
    float a = acoef[nc], b = bcoef[nc];
    float4 m = ((const float4*)out)[i];
    float4 xx = ((const float4*)x)[i];
    float4 r;
    r.x = fmaxf(fmaf(a, m.x, b) + xx.x, 0.f);
    r.y = fmaxf(fmaf(a, m.y, b) + xx.y, 0.f);
    r.z = fmaxf(fmaf(a, m.z, b) + xx.z, 0.f);
    r.w = fmaxf(fmaf(a, m.w, b) + xx.w, 0.f);
    ((float4*)out)[i] = r;
}

extern "C" void kernel_launch(void* const* d_in, const int* in_sizes, int n_in,
                              void* d_out, int out_size, void* d_ws, size_t ws_size,
                              hipStream_t stream) {
    const float* x = (const float*)d_in[0];
    const float* Ab = (const float*)d_in[1];
    const float* DA = (const float*)d_in[2];
    const float* DAM = (const float*)d_in[3];
    const float* convw = (const float*)d_in[4];
    const float* convb = (const float*)d_in[5];
    const float* sew = (const float*)d_in[6];
    const float* gamma = (const float*)d_in[7];
    const float* beta = (const float*)d_in[8];
    float* out = (float*)d_out;
    float* ws = (float*)d_ws;

    gcn_prep<<<16, 256, 0, stream>>>(Ab, DA, DAM, convw, ws);
    gcn_pass1<<<256, 512, 0, stream>>>(x, convb, ws, out, ws + WS_PSUM, ws + WS_SSQ);
    gcn_stats<<<1, 256, 0, stream>>>(sew, gamma, beta, ws);
    const int total4 = (NN * COUT * TT * VV) / 4;
    gcn_final<<<(total4 + 255) / 256, 256, 0, stream>>>(x, ws, out);
}

// Round 3
// 117.370 us; speedup vs baseline: 2.8279x; 2.8279x over previous
//
#include <hip/hip_runtime.h>
#include <math.h>

// Dims (hard-coded per reference setup_inputs)
#define NN 64
#define CIN 64
#define COUT 64
#define TT 256
#define VV 17
#define NSUB 3
#define GG 8

// ws layout (float units):
//  [0      .. 12288)  Mb   u16[3][8][32w][32k]  (bf16, Mb[s][g][w][k] = M[v=k][w], zero for k>=17 or w>=17)
//  [12288  .. 18432)  Wbf  u16[192][64]         (bf16 conv weight)
//  [18432  .. 22528)  psum f32[64][64]
//  [22528  .. 26624)  ssq  f32[64][64]
//  after pass1 (Mb/Wbf dead):
//  [0      .. 4096)   acoef f32[64][64]
//  [4096   .. 8192)   bcoef f32[64][64]
#define WS_MB 0
#define WS_WBF 12288
#define WS_PSUM 18432
#define WS_SSQ 22528
#define WS_ACOEF 0
#define WS_BCOEF 4096

typedef short bh8 __attribute__((ext_vector_type(8)));
typedef float f32x4 __attribute__((ext_vector_type(4)));
typedef float f32x16 __attribute__((ext_vector_type(16)));
typedef unsigned short u16t;

__device__ __forceinline__ unsigned bf16r(float f) {
    unsigned u = __builtin_bit_cast(unsigned, f);
    return (u + 0x7fffu + ((u >> 16) & 1u)) >> 16;  // RNE f32->bf16
}
__device__ __forceinline__ float bf2f(unsigned us) {
    return __builtin_bit_cast(float, us << 16);
}

// ---------------- Kernel 1: prep — bf16 M-table (K=32 padded), bf16 W, zero stats ----------------
__device__ __forceinline__ float mfull(const float* Ab, const float* DA, const float* DAM,
                                       int s, int g, int v, int w) {
    const unsigned bad = (1u << 3) | (1u << 6) | (1u << 7) | (1u << 9) | (1u << 10);
    float mask = ((v >= 12 && w >= 12) || ((bad >> v) & 1) || ((bad >> w) & 1)) ? 0.f : 1.f;
    int src = ((s * GG + g) * VV + v) * VV + w;
    return Ab[(s * VV + v) * VV + w] + DA[src] + DAM[src] * mask + 0.04f;
}

__global__ void gcn_prep(const float* __restrict__ Ab, const float* __restrict__ DA,
                         const float* __restrict__ DAM, const float* __restrict__ convw,
                         float* __restrict__ ws) {
    int t0 = blockIdx.x * 256 + threadIdx.x;
    int stride = gridDim.x * 256;
    u16t* wbf = (u16t*)(ws + WS_WBF);
    for (int i = t0; i < 192 * 64; i += stride) wbf[i] = (u16t)bf16r(convw[i]);
    u16t* mb = (u16t*)(ws + WS_MB);
    for (int i = t0; i < NSUB * GG * 32 * 32; i += stride) {
        int k = i & 31, w = (i >> 5) & 31, g = (i >> 10) & 7, s = i >> 13;
        u16t val = 0;
        if (w < VV && k < VV) val = (u16t)bf16r(mfull(Ab, DA, DAM, s, g, k, w));
        mb[i] = val;
    }
    for (int i = t0; i < 8192; i += stride) ws[WS_PSUM + i] = 0.f;
}

// ---------------- Kernel 2: fused conv(MFMA) + adjacency(MFMA) + coalesced m2 store + stats ----------------
// Tile = (n, 16 timesteps) -> 272 tv-columns. Block b handles 4 tiles of the same n.
// LDS: xsT [272 col][72 ci-pad] bf16 = 39168 B (overlaid by bf16 staging [64][272] = 34816 B in epilogue)
//      Wl  [192][72] bf16          = 27648 B
//      mt  [64 co][16 t][40 v] bf16= 82944 B (pad stride 648 u16/co; v 17..31 stay zero)
__global__ __launch_bounds__(512, 2) void gcn_pass1(const float* __restrict__ x,
                                                    const float* __restrict__ convb,
                                                    const float* __restrict__ ws,
                                                    float* __restrict__ out,
                                                    float* __restrict__ psum,
                                                    float* __restrict__ ssq) {
    __shared__ u16t xsT[272 * 72];
    __shared__ u16t Wl[192 * 72];
    __shared__ u16t mt[64 * 648];

    const int tid = threadIdx.x;
    const int wave = tid >> 6;  // 0..7 == adjacency group g
    const int l = tid & 63;
    const int c16 = l & 15;
    const int q4 = (l >> 4) & 3;
    const int c32 = l & 31;
    const int hi = l >> 5;
    const int n = blockIdx.x >> 2;

    const u16t* mbg = (const u16t*)(ws + WS_MB);
    const u16t* wbfg = (const u16t*)(ws + WS_WBF);

    // ---- one-time LDS init: copy W (repack to stride 72), zero mt ----
    for (int j = tid; j < 192 * 32; j += 512) {
        int row = j >> 5, c2 = j & 31;
        ((unsigned*)Wl)[row * 36 + c2] = ((const unsigned*)wbfg)[j];
    }
    for (int j = tid; j < (64 * 648) / 2; j += 512) ((unsigned*)mt)[j] = 0u;

    // ---- adjacency B-fragments (registers, once per kernel) ----
    bh8 Badj[3], Badj2[3];
#pragma unroll
    for (int s = 0; s < 3; ++s) {
        const u16t* mrow = &mbg[((s * 8 + wave) * 32 + c32) * 32 + 8 * hi];
        Badj[s] = *(const bh8*)mrow;        // k = v 0..15
        Badj2[s] = *(const bh8*)(mrow + 16);  // k = v 16..31 (only v=16 nonzero)
    }
    const int cfs[3] = {wave, wave + 8, 16};

    float acc1[8], acc2[8];
#pragma unroll
    for (int j = 0; j < 8; ++j) { acc1[j] = 0.f; acc2[j] = 0.f; }

    __syncthreads();

    for (int k4 = 0; k4 < 4; ++k4) {
        const int tt = 4 * (blockIdx.x & 3) + k4;

        // ---- stage x tile transposed: xsT[col][ci], bf16 pairs packed in u32 ----
        const float* xb = x + (size_t)n * 64 * 4352 + tt * 272;
#pragma unroll
        for (int k = 0; k < 4; ++k) {
            int cp = wave + 8 * k;  // ci-pair index
            const float* r0 = xb + (2 * cp) * 4352;
            const float* r1 = r0 + 4352;
#pragma unroll
            for (int cc = 0; cc < 5; ++cc) {
                int col = cc * 64 + l;
                if (col < 272) {
                    unsigned p = bf16r(r0[col]) | (bf16r(r1[col]) << 16);
                    ((unsigned*)xsT)[col * 36 + cp] = p;
                }
            }
        }
        __syncthreads();

        // ---- conv B-fragments from xsT (s-invariant) ----
        bh8 Bc[3][2];
#pragma unroll
        for (int cfi = 0; cfi < 3; ++cfi)
#pragma unroll
            for (int ks = 0; ks < 2; ++ks)
                Bc[cfi][ks] = *(const bh8*)&xsT[(16 * cfs[cfi] + c16) * 72 + 32 * ks + 8 * q4];

        f32x16 D2[4];
#pragma unroll
        for (int p = 0; p < 4; ++p) D2[p] = 0;

#pragma unroll
        for (int s = 0; s < 3; ++s) {
            // ---- conv MFMA: rows = 64 co of subset s; cf16 deduped (wave==rf owns it) ----
            f32x4 Dc[4][3];
#pragma unroll
            for (int rf = 0; rf < 4; ++rf) {
                f32x4 bias = *(const f32x4*)(convb + s * 64 + 16 * rf + 4 * q4);
#pragma unroll
                for (int cfi = 0; cfi < 3; ++cfi) Dc[rf][cfi] = bias;
            }
#pragma unroll
            for (int rf = 0; rf < 4; ++rf)
#pragma unroll
                for (int ks = 0; ks < 2; ++ks) {
                    bh8 A = *(const bh8*)&Wl[(s * 64 + 16 * rf + c16) * 72 + 32 * ks + 8 * q4];
                    Dc[rf][0] = __builtin_amdgcn_mfma_f32_16x16x32_bf16(A, Bc[0][ks], Dc[rf][0], 0, 0, 0);
                    Dc[rf][1] = __builtin_amdgcn_mfma_f32_16x16x32_bf16(A, Bc[1][ks], Dc[rf][1], 0, 0, 0);
                    if (wave == rf)
                        Dc[rf][2] = __builtin_amdgcn_mfma_f32_16x16x32_bf16(A, Bc[2][ks], Dc[rf][2], 0, 0, 0);
                }
            if (s > 0) __syncthreads();  // prev adjacency reads done before overwriting mt
            // ---- store m (bf16) into mt[co][t][40v] ----
#pragma unroll
            for (int rf = 0; rf < 4; ++rf)
#pragma unroll
                for (int cfi = 0; cfi < 3; ++cfi) {
                    if (cfi == 2 && wave != rf) continue;
                    int col = 16 * cfs[cfi] + c16;
                    int t = (col * 241) >> 12;  // col/17, exact for col<272
                    int v = col - 17 * t;
                    int base = (16 * rf + 4 * q4) * 648 + t * 40 + v;
#pragma unroll
                    for (int i = 0; i < 4; ++i)
                        mt[base + i * 648] = (u16t)bf16r(Dc[rf][cfi][i]);
                }
            __syncthreads();

            // ---- adjacency MFMA: 2 per p (v0..15, v16..31-padded) ----
#pragma unroll
            for (int p = 0; p < 4; ++p) {
                int coA = wave + 8 * (2 * p + (c32 >> 4));
                int base = coA * 648 + c16 * 40 + 8 * hi;
                bh8 a0 = *(const bh8*)&mt[base];
                bh8 a1 = *(const bh8*)&mt[base + 16];
                D2[p] = __builtin_amdgcn_mfma_f32_32x32x16_bf16(a0, Badj[s], D2[p], 0, 0, 0);
                D2[p] = __builtin_amdgcn_mfma_f32_32x32x16_bf16(a1, Badj2[s], D2[p], 0, 0, 0);
            }
        }

        // ---- epilogue: stage D2 as bf16 into xsT region, accumulate stats ----
        u16t* stg = xsT;  // [64 co][272] bf16 = 34816 B (xsT dead: Bc already in regs)
#pragma unroll
        for (int p = 0; p < 4; ++p)
#pragma unroll
            for (int reg = 0; reg < 16; ++reg) {
                int row = (reg & 3) + 8 * (reg >> 2) + 4 * hi;
                int cosel = row >> 4;
                int t = row & 15;
                int co = wave + 8 * (2 * p + cosel);
                float val = D2[p][reg];
                if (c32 < 17) stg[co * 272 + t * 17 + c32] = (u16t)bf16r(val);
                if (cosel == 0) { acc1[2 * p] += val; acc2[2 * p] += val * val; }
                else            { acc1[2 * p + 1] += val; acc2[2 * p + 1] += val * val; }
            }
        __syncthreads();

        // ---- cooperative coalesced f32 store of m2 ----
        float* ob = out + ((size_t)n * 64) * 4352 + tt * 272;
#pragma unroll
        for (int it = 0; it < 9; ++it) {
            int c = tid + 512 * it;
            if (c < 4352) {
                int co = c / 68;
                int pos = (c - co * 68) * 4;
                uint2 u = *(const uint2*)&stg[co * 272 + pos];
                float4 v;
                v.x = bf2f(u.x & 0xffffu);
                v.y = bf2f(u.x >> 16);
                v.z = bf2f(u.y & 0xffffu);
                v.w = bf2f(u.y >> 16);
                *(float4*)(ob + co * 4352 + pos) = v;
            }
        }
        __syncthreads();
    }

    // ---- block-level stats reduce (once): co = wave + 8*j ----
#pragma unroll
    for (int j = 0; j < 8; ++j) {
        float s1 = acc1[j], s2 = acc2[j];
#pragma unroll
        for (int m = 1; m < 64; m <<= 1) {
            s1 += __shfl_xor(s1, m);
            s2 += __shfl_xor(s2, m);
        }
        if (l == 0) {
            atomicAdd(&psum[n * 64 + wave + 8 * j], s1);
            atomicAdd(&ssq[n * 64 + wave + 8 * j], s2);
        }
    }
}

// ---------------- Kernel 3: SE gate + BN stats -> per-(n,c) affine coefs ----------------
__global__ void gcn_stats(const float* __restrict__ se_w, const float* __restrict__ gamma,
                          const float* __restrict__ beta, float* __restrict__ ws) {
    __shared__ float ps[4096], sc[4096], q2s[4096];
    __shared__ float mu_s[64], inv_s[64];
    int tid = threadIdx.x;
    const float* psum = ws + WS_PSUM;
    const float* ssq = ws + WS_SSQ;
    float* acoef = ws + WS_ACOEF;
    float* bcoef = ws + WS_BCOEF;
    for (int i = tid; i < 4096; i += 256) ps[i] = psum[i] * (1.f / (TT * VV));
    __syncthreads();
    float w0 = se_w[0], w1 = se_w[1], w2 = se_w[2];
    for (int i = tid; i < 4096; i += 256) {
        int c = i & 63;
        float pm = (c > 0) ? ps[i - 1] : 0.f;
        float pp = (c < 63) ? ps[i + 1] : 0.f;
        float gg = w0 * pm + w1 * ps[i] + w2 * pp;
        float s = 1.f + 1.f / (1.f + expf(-gg));
        sc[i] = s;
        q2s[i] = s * s * ssq[i];
    }
    __syncthreads();
    if (tid < 64) {
        float mu = 0.f, e2 = 0.f;
        for (int nn = 0; nn < 64; ++nn) {
            mu += sc[nn * 64 + tid] * ps[nn * 64 + tid];
            e2 += q2s[nn * 64 + tid];
        }
        mu *= (1.f / 64.f);
        e2 *= (1.f / (64.f * TT * VV));
        float var = e2 - mu * mu;
        mu_s[tid] = mu;
        inv_s[tid] = rsqrtf(var + 1e-5f);
    }
    __syncthreads();
    for (int i = tid; i < 4096; i += 256) {
        int c = i & 63;
        float gin = gamma[c] * inv_s[c];
        acoef[i] = gin * sc[i];
        bcoef[i] = beta[c] - gin * mu_s[c];
    }
}

// ---------------- Kernel 4: out = relu(a*m2 + b + x), in-place on d_out ----------------
__global__ __launch_bounds__(256) void gcn_final(const float* __restrict__ x,
                                                 const float* __restrict__ ws,
                                                 float* __restrict__ out) {
    const float* acoef = ws + WS_ACOEF;
    const float* bcoef = ws + WS_BCOEF;
    int i = blockIdx.x * 256 + threadIdx.x;
    const int total4 = (NN * COUT * TT * VV) / 4;
    if (i >= total4) return;
    int nc = i / ((TT * VV) / 4);
    float a = acoef[nc], b = bcoef[nc];
    float4 m = ((const float4*)out)[i];
    float4 xx = ((const float4*)x)[i];
    float4 r;
    r.x = fmaxf(fmaf(a, m.x, b) + xx.x, 0.f);
    r.y = fmaxf(fmaf(a, m.y, b) + xx.y, 0.f);
    r.z = fmaxf(fmaf(a, m.z, b) + xx.z, 0.f);
    r.w = fmaxf(fmaf(a, m.w, b) + xx.w, 0.f);
    ((float4*)out)[i] = r;
}

extern "C" void kernel_launch(void* const* d_in, const int* in_sizes, int n_in,
                              void* d_out, int out_size, void* d_ws, size_t ws_size,
                              hipStream_t stream) {
    const float* x = (const float*)d_in[0];
    const float* Ab = (const float*)d_in[1];
    const float* DA = (const float*)d_in[2];
    const float* DAM = (const float*)d_in[3];
    const float* convw = (const float*)d_in[4];
    const float* convb = (const float*)d_in[5];
    const float* sew = (const float*)d_in[6];
    const float* gamma = (const float*)d_in[7];
    const float* beta = (const float*)d_in[8];
    float* out = (float*)d_out;
    float* ws = (float*)d_ws;

    gcn_prep<<<16, 256, 0, stream>>>(Ab, DA, DAM, convw, ws);
    gcn_pass1<<<256, 512, 0, stream>>>(x, convb, ws, out, ws + WS_PSUM, ws + WS_SSQ);
    gcn_stats<<<1, 256, 0, stream>>>(sew, gamma, beta, ws);
    const int total4 = (NN * COUT * TT * VV) / 4;
    gcn_final<<<(total4 + 255) / 256, 256, 0, stream>>>(x, ws, out);
}